// Round 9
// baseline (795.385 us; speedup 1.0000x reference)
//
#include <hip/hip_runtime.h>
#include <hip/hip_bf16.h>

// ---------------------------------------------------------------------------
// DenoiseGCN fused kernel for MI355X (gfx950) — round 9.
// R8 post-mortem: stable at VALU 49 / MFMA 22 / bank-conflict 5e7. Dominant
// cost = epilogue: 40 scalar b16 LDS writes + 40 scalar b16 reads per
// thread/layer at 4-way conflicts + per-access address VALU.
// Fix: INTERLEAVED column pairing — MFMA tile0 loads Wt row n0+2*m15, tile1
// row n0+2*m15+1, so acc[mt][0][j] / acc[mt][1][j] are ADJACENT columns at
// one row -> epilogue packs them into ONE u32 (20 b32 writes + 20 b32 reads,
// measured-free 2-way banking; residual unpack = 2 bit-ops; cvt pairs into
// v_cvt_pk_bf16_f32). Physical LDS layout / staging / A-reads / agg shfl /
// head2 unchanged. Everything else identical to R8 (no-spill discipline).
// ---------------------------------------------------------------------------

typedef __attribute__((ext_vector_type(8))) short bf16x8;
typedef __attribute__((ext_vector_type(4))) float f32x4;

#define NV 1024

// ws element offsets (bf16 elements)
#define OFF_W0T   0        // [256][160] merged: k<128 temb (W0+res0), 128-129 W0c, 130-131 res0c
#define OFF_W1T   40960    // [256][256], pre-scaled by 1/3
#define OFF_W2T   106496   // pre-scaled by 1/3
#define OFF_W3T   172032   // pre-scaled by 1/3
#define OFF_HW1T  237568
#define OFF_HW2T  303104   // [16][256]
#define OFF_TEMB  307200   // [512][128]
#define PREP_ELEMS 307200

__device__ __forceinline__ float bf2f(short u){
  union { unsigned int i; float f; } v;
  v.i = ((unsigned int)(unsigned short)u) << 16;
  return v.f;
}
__device__ __forceinline__ short f2bf(float f){
  __hip_bfloat16 h = __float2bfloat16(f);
  return *reinterpret_cast<short*>(&h);
}
__device__ __forceinline__ float silu_f(float v){
  float e = __expf(-v);
  return v * __builtin_amdgcn_rcpf(1.f + e);
}
__device__ __forceinline__ f32x4 zero4(){ f32x4 z = {0.f,0.f,0.f,0.f}; return z; }
// pack silu(s0), silu(s1) -> 2 bf16 in one u32 (compiler: v_cvt_pk_bf16_f32)
__device__ __forceinline__ unsigned int pack2_silu(float s0, float s1){
  return (unsigned int)(unsigned short)f2bf(silu_f(s0))
       | ((unsigned int)(unsigned short)f2bf(silu_f(s1)) << 16);
}

// ---------------------------------------------------------------------------
// prep: fp32 weights -> bf16, transposed to [N][K] (k contiguous) with pads.
// W0T merged (see header). W1..W3 pre-scaled by 1/3 (agg commutes with W).
// ---------------------------------------------------------------------------
__global__ void prep_kernel(const float* __restrict__ W0, const float* __restrict__ res0,
                            const float* __restrict__ W1, const float* __restrict__ W2,
                            const float* __restrict__ W3, const float* __restrict__ hW1,
                            const float* __restrict__ hW2, short* __restrict__ ws){
  int idx = blockIdx.x * 256 + threadIdx.x;
  if (idx >= PREP_ELEMS) return;
  float v = 0.f;
  if (idx < 40960){
    int n = idx / 160, k = idx - n * 160;
    if (k < 128)      v = W0[(k + 2) * 256 + n] + res0[(k + 2) * 256 + n];
    else if (k < 130) v = W0[(k - 128) * 256 + n];
    else if (k < 132) v = res0[(k - 130) * 256 + n];
  } else if (idx < 303104){
    int rem = idx - 40960;
    int seg = rem >> 16;
    int r2 = rem & 65535;
    int n = r2 >> 8, k = r2 & 255;
    const float* src = (seg == 0) ? W1 : (seg == 1) ? W2 : (seg == 2) ? W3 : hW1;
    v = src[k * 256 + n];
    if (seg < 3) v *= (1.f / 3.f);
  } else {
    int rem = idx - 303104;
    int n = rem >> 8, k = rem & 255;
    if (n < 2) v = hW2[k * 2 + n];
  }
  ws[idx] = f2bf(v);
}

// ---------------------------------------------------------------------------
// temb: silu(sinusoidal(t) @ time_W + time_b) per batch element -> bf16
// ---------------------------------------------------------------------------
__global__ void temb_kernel(const int* __restrict__ t, const float* __restrict__ tW,
                            const float* __restrict__ tb, short* __restrict__ temb){
  __shared__ float sc[128];
  int b = blockIdx.x, n = threadIdx.x;  // 128 threads
  float tv = (float)t[b];
  {
    int j = n & 63;
    float fr = __expf(-9.210340371976184f * (float)j * (1.f / 63.f));
    float ang = tv * fr;
    sc[n] = (n < 64) ? sinf(ang) : cosf(ang);
  }
  __syncthreads();
  float acc = tb[n];
  #pragma unroll 8
  for (int k = 0; k < 128; ++k) acc += sc[k] * tW[k * 128 + n];
  temb[b * 128 + n] = f2bf(silu_f(acc));
}

// ---------------------------------------------------------------------------
// mm2 (interleaved cols): acc[mt][0] ~ col n0+2*m15, acc[mt][1] ~ col
// n0+2*m15+1. B-frag tile0 = Wt row n0+2*m15, tile1 = next row (the MFMA's
// abstract col index = lane&15 for both the B-frag load and the C-frag, so
// any col<->lane assignment is self-consistent). A-frag/C rows unchanged:
// row = 16*mt + (l&15) for A, (l>>4)*4+j for C. unroll 2 caps weight
// hoisting (full unroll spilled — R4).
// ---------------------------------------------------------------------------
template<int KPAD>
__device__ __forceinline__ void mm2(const char* hbuf, const short* __restrict__ Wt,
                                    int m15, int g, int n0, f32x4 acc[5][2]){
  const short* wb = Wt + (n0 + 2 * m15) * KPAD + g * 8;
  #pragma unroll 2
  for (int ks = 0; ks < KPAD / 32; ++ks){
    bf16x8 bf0 = *(const bf16x8*)(wb + ks * 32);
    bf16x8 bf1 = *(const bf16x8*)(wb + KPAD + ks * 32);
    const int kb = ks * 64 + g * 16;
    #pragma unroll
    for (int mt = 0; mt < 5; ++mt){
      const int row = mt * 16 + m15;
      bf16x8 a = *(const bf16x8*)(hbuf + row * 512 + (kb ^ ((row & 7) << 4)));
      acc[mt][0] = __builtin_amdgcn_mfma_f32_16x16x32_bf16(a, bf0, acc[mt][0], 0, 0, 0);
      acc[mt][1] = __builtin_amdgcn_mfma_f32_16x16x32_bf16(a, bf1, acc[mt][1], 0, 0, 0);
    }
  }
}

// ---------------------------------------------------------------------------
// Fused GCN. Grid (16, 512): x = 64-vertex tile, y = batch. 512 thr = 8 waves,
// wave w owns output cols [32w, 32w+32) (interleaved pairing inside). LDS:
// hA + hB, each 80x256 bf16 (40KB). Row r <-> vertex (v0 + r - 4) mod 1024;
// valid window shrinks 1/layer; out rows 4..67. Buffer flow:
// stage->hA; L0: hA->hB; L1: hB->hA; L2: hA->hB; L3: hB->hA; head1: hA->hB;
// head2: hB->out. ONE barrier per phase; residual for layer L re-read from
// bin (read-only during the phase — no hazard, no regs).
// ---------------------------------------------------------------------------
__global__ __launch_bounds__(512, 4)
void gcn_fused(const float* __restrict__ x, const short* __restrict__ ws,
               const float* __restrict__ b0p, const float* __restrict__ b1p,
               const float* __restrict__ b2p, const float* __restrict__ b3p,
               const float* __restrict__ hb1p, const float* __restrict__ hb2p,
               float* __restrict__ out){
  extern __shared__ char lds[];
  char* const hA = lds;
  char* const hB = lds + 40960;
  const int tid = threadIdx.x;
  const int lane = tid & 63, wid = tid >> 6;
  const int m15 = lane & 15, g = lane >> 4;
  const int n0 = wid * 32;
  const int cb2 = (n0 + 2 * m15) * 2;   // byte col of this thread's col pair
  const int b = blockIdx.y, v0 = blockIdx.x * 64;

  // ---- stage h0' into hA: temb chunks 0-15; chunk 16 = [cagg0,cagg1,c0,c1,0..];
  //      chunks 17-23 zero. (Layer-0 A-row = [temb, cagg, c] vs merged W0T.)
  {
    const short* tembp = ws + OFF_TEMB + b * 128;
    for (int task = tid; task < 72 * 16; task += 512){
      int r = task >> 4, ck = (task & 15) * 16;
      *(bf16x8*)(hA + r * 512 + (ck ^ ((r & 7) << 4))) =
          *(const bf16x8*)(tembp + (task & 15) * 8);
    }
    for (int task = tid; task < 80 * 8; task += 512){
      int r = task >> 3, q = task & 7;
      bf16x8 v = {0, 0, 0, 0, 0, 0, 0, 0};
      if (q == 0 && r < 72){
        const float* xb = x + b * 2048;
        int vm = (v0 + r - 5) & (NV - 1);
        int vc = (v0 + r - 4) & (NV - 1);
        int vp = (v0 + r - 3) & (NV - 1);
        float c0m = xb[vm * 2], c1m = xb[vm * 2 + 1];
        float c0c = xb[vc * 2], c1c = xb[vc * 2 + 1];
        float c0p = xb[vp * 2], c1p = xb[vp * 2 + 1];
        v[0] = f2bf((c0m + c0c + c0p) * (1.f / 3.f));
        v[1] = f2bf((c1m + c1c + c1p) * (1.f / 3.f));
        v[2] = f2bf(c0c);
        v[3] = f2bf(c1c);
      }
      *(bf16x8*)(hA + r * 512 + (((16 + q) * 16) ^ ((r & 7) << 4))) = v;
    }
  }
  __syncthreads();

  f32x4 acc[5][2];

  // ---- layer 0: ONE matmul (merged weights); h1 = silu(acc+b0): hA -> hB ----
  {
    const float2 bias = *(const float2*)(b0p + n0 + 2 * m15);
    #pragma unroll
    for (int mt = 0; mt < 5; ++mt){ acc[mt][0] = zero4(); acc[mt][1] = zero4(); }
    mm2<160>(hA, ws + OFF_W0T, m15, g, n0, acc);
    #pragma unroll
    for (int mt = 0; mt < 5; ++mt){
      const int row0 = mt * 16 + g * 4;
      #pragma unroll
      for (int j = 0; j < 4; ++j){
        const int row = row0 + j;
        const int ad = row * 512 + (cb2 ^ ((row & 7) << 4));
        *(unsigned int*)(hB + ad) =
            pack2_silu(acc[mt][0][j] + bias.x, acc[mt][1][j] + bias.y);
      }
    }
  }
  __syncthreads();

  // ---- layers 1..3: h = silu(agg(h@W') + b + h); W' pre-scaled by 1/3;
  //      agg via in-reg shfl; residual read from bin (read-only this phase) ----
  #pragma unroll
  for (int L = 0; L < 3; ++L){
    const char* bin  = (L & 1) ? hA : hB;
    char*       bout = (L & 1) ? hB : hA;
    const short* Wt = ws + (L == 0 ? OFF_W1T : L == 1 ? OFF_W2T : OFF_W3T);
    const float* bp = (L == 0 ? b1p : L == 1 ? b2p : b3p);
    const float2 bias = *(const float2*)(bp + n0 + 2 * m15);
    #pragma unroll
    for (int mt = 0; mt < 5; ++mt){ acc[mt][0] = zero4(); acc[mt][1] = zero4(); }
    mm2<256>(bin, Wt, m15, g, n0, acc);
    #pragma unroll
    for (int mt = 0; mt < 5; ++mt){
      // ring neighbors at the j=0 / j=3 group boundary (row-1 / row+1);
      // source pre-selects mt-1 at g==3 / mt+1 at g==0
      float pm0[2], pp3[2];
      #pragma unroll
      for (int nt = 0; nt < 2; ++nt){
        float upv = (g == 3) ? acc[mt > 0 ? mt - 1 : 0][nt][3] : acc[mt][nt][3];
        pm0[nt] = __shfl(upv, (lane + 48) & 63);
        float dnv = (g == 0) ? acc[mt < 4 ? mt + 1 : 4][nt][0] : acc[mt][nt][0];
        pp3[nt] = __shfl(dnv, (lane + 16) & 63);
      }
      const int row0 = mt * 16 + g * 4;
      #pragma unroll
      for (int j = 0; j < 4; ++j){
        const int row = row0 + j;
        const int ad = row * 512 + (cb2 ^ ((row & 7) << 4));
        const unsigned int rr = *(const unsigned int*)(bin + ad);
        union { unsigned int i; float f; } re, ro;
        re.i = rr << 16;            // residual, even col
        ro.i = rr & 0xffff0000u;    // residual, odd col
        float p0 = (j == 0) ? pm0[0] : acc[mt][0][j - 1];
        float n0v = (j == 3) ? pp3[0] : acc[mt][0][j + 1];
        float p1 = (j == 0) ? pm0[1] : acc[mt][1][j - 1];
        float n1v = (j == 3) ? pp3[1] : acc[mt][1][j + 1];
        float s0 = p0 + acc[mt][0][j] + n0v + bias.x + re.f;
        float s1 = p1 + acc[mt][1][j] + n1v + bias.y + ro.f;
        *(unsigned int*)(bout + ad) = pack2_silu(s0, s1);
      }
    }
    __syncthreads();
  }
  // h4 now in hA.

  // ---- head part 1: u = silu(h4 @ hW1 + hb1): hA -> hB ----
  {
    const float2 bias = *(const float2*)(hb1p + n0 + 2 * m15);
    #pragma unroll
    for (int mt = 0; mt < 5; ++mt){ acc[mt][0] = zero4(); acc[mt][1] = zero4(); }
    mm2<256>(hA, ws + OFF_HW1T, m15, g, n0, acc);
    #pragma unroll
    for (int mt = 0; mt < 5; ++mt){
      const int row0 = mt * 16 + g * 4;
      #pragma unroll
      for (int j = 0; j < 4; ++j){
        const int row = row0 + j;
        const int ad = row * 512 + (cb2 ^ ((row & 7) << 4));
        *(unsigned int*)(hB + ad) =
            pack2_silu(acc[mt][0][j] + bias.x, acc[mt][1][j] + bias.y);
      }
    }
    __syncthreads();
  }

  // ---- head part 2 (wave 0 only): out = u @ hW2 + hb2, rows 4..67 ----
  if (wid == 0){
    f32x4 a2[5];
    #pragma unroll
    for (int mt = 0; mt < 5; ++mt) a2[mt] = zero4();
    const short* wb = ws + OFF_HW2T + m15 * 256 + g * 8;
    #pragma unroll 2
    for (int ks = 0; ks < 8; ++ks){
      bf16x8 bfr = *(const bf16x8*)(wb + ks * 32);
      const int kb = ks * 64 + g * 16;
      #pragma unroll
      for (int mt = 0; mt < 5; ++mt){
        const int row = mt * 16 + m15;
        bf16x8 a = *(const bf16x8*)(hB + row * 512 + (kb ^ ((row & 7) << 4)));
        a2[mt] = __builtin_amdgcn_mfma_f32_16x16x32_bf16(a, bfr, a2[mt], 0, 0, 0);
      }
    }
    if (m15 < 2){
      float bias = hb2p[m15];
      #pragma unroll
      for (int mt = 0; mt < 5; ++mt)
        #pragma unroll
        for (int j = 0; j < 4; ++j){
          int row = mt * 16 + g * 4 + j;
          if (row >= 4 && row < 68)
            out[b * 2048 + (v0 + row - 4) * 2 + m15] = a2[mt][j] + bias;
        }
    }
  }
}

// ---------------------------------------------------------------------------
extern "C" void kernel_launch(void* const* d_in, const int* in_sizes, int n_in,
                              void* d_out, int out_size, void* d_ws, size_t ws_size,
                              hipStream_t stream){
  const float* x   = (const float*)d_in[0];
  const int*   t   = (const int*)  d_in[1];
  const float* tW  = (const float*)d_in[2];
  const float* tb  = (const float*)d_in[3];
  const float* W0  = (const float*)d_in[4];
  const float* b0  = (const float*)d_in[5];
  const float* W1  = (const float*)d_in[6];
  const float* b1  = (const float*)d_in[7];
  const float* W2  = (const float*)d_in[8];
  const float* b2  = (const float*)d_in[9];
  const float* W3  = (const float*)d_in[10];
  const float* b3  = (const float*)d_in[11];
  const float* res0= (const float*)d_in[12];
  const float* hW1 = (const float*)d_in[13];
  const float* hb1 = (const float*)d_in[14];
  const float* hW2 = (const float*)d_in[15];
  const float* hb2 = (const float*)d_in[16];
  short* ws  = (short*)d_ws;
  float* out = (float*)d_out;

  hipFuncSetAttribute((const void*)gcn_fused,
                      hipFuncAttributeMaxDynamicSharedMemorySize, 81920);

  prep_kernel<<<dim3((PREP_ELEMS + 255) / 256), dim3(256), 0, stream>>>(
      W0, res0, W1, W2, W3, hW1, hW2, ws);
  temb_kernel<<<dim3(512), dim3(128), 0, stream>>>(t, tW, tb, ws + OFF_TEMB);
  gcn_fused<<<dim3(16, 512), dim3(512), 81920, stream>>>(
      x, ws, b0, b1, b2, b3, hb1, hb2, out);
}

// Round 10
// 777.551 us; speedup vs baseline: 1.0229x; 1.0229x over previous
//
#include <hip/hip_runtime.h>
#include <hip/hip_bf16.h>

// ---------------------------------------------------------------------------
// DenoiseGCN fused kernel for MI355X (gfx950) — round 10.
// R9 post-mortem: bank-conflict counter is IDENTICAL (4.981e7) across R6-R9
// -> conflicts are the mm2 A-read's structural 8-way (LDS BW floor), not the
// epilogue; attacking them was a dead end. Real bottleneck: L2 weight-load
// latency chains in mm2 (2-deep prefetch, ~300cyc exposed 4x/matmul) at only
// 4 waves/SIMD (reg-capped).
// Fixes: (1) mm2 unroll 4 -> 8 loads in flight, halves exposed latency steps
// (VGPR budget ~124/128 — tripwire: WRITE_SIZE). (2) head2 split across
// waves 0-4 (one mt each; a2 20->4 regs) — kills the single-wave tail.
// ---------------------------------------------------------------------------

typedef __attribute__((ext_vector_type(8))) short bf16x8;
typedef __attribute__((ext_vector_type(4))) float f32x4;

#define NV 1024

// ws element offsets (bf16 elements)
#define OFF_W0T   0        // [256][160] merged: k<128 temb (W0+res0), 128-129 W0c, 130-131 res0c
#define OFF_W1T   40960    // [256][256], pre-scaled by 1/3
#define OFF_W2T   106496   // pre-scaled by 1/3
#define OFF_W3T   172032   // pre-scaled by 1/3
#define OFF_HW1T  237568
#define OFF_HW2T  303104   // [16][256]
#define OFF_TEMB  307200   // [512][128]
#define PREP_ELEMS 307200

__device__ __forceinline__ float bf2f(short u){
  union { unsigned int i; float f; } v;
  v.i = ((unsigned int)(unsigned short)u) << 16;
  return v.f;
}
__device__ __forceinline__ short f2bf(float f){
  __hip_bfloat16 h = __float2bfloat16(f);
  return *reinterpret_cast<short*>(&h);
}
__device__ __forceinline__ float silu_f(float v){
  float e = __expf(-v);
  return v * __builtin_amdgcn_rcpf(1.f + e);
}
__device__ __forceinline__ f32x4 zero4(){ f32x4 z = {0.f,0.f,0.f,0.f}; return z; }
// pack silu(s0), silu(s1) -> 2 bf16 in one u32
__device__ __forceinline__ unsigned int pack2_silu(float s0, float s1){
  return (unsigned int)(unsigned short)f2bf(silu_f(s0))
       | ((unsigned int)(unsigned short)f2bf(silu_f(s1)) << 16);
}

// ---------------------------------------------------------------------------
// prep: fp32 weights -> bf16, transposed to [N][K] (k contiguous) with pads.
// W0T merged (see header). W1..W3 pre-scaled by 1/3 (agg commutes with W).
// ---------------------------------------------------------------------------
__global__ void prep_kernel(const float* __restrict__ W0, const float* __restrict__ res0,
                            const float* __restrict__ W1, const float* __restrict__ W2,
                            const float* __restrict__ W3, const float* __restrict__ hW1,
                            const float* __restrict__ hW2, short* __restrict__ ws){
  int idx = blockIdx.x * 256 + threadIdx.x;
  if (idx >= PREP_ELEMS) return;
  float v = 0.f;
  if (idx < 40960){
    int n = idx / 160, k = idx - n * 160;
    if (k < 128)      v = W0[(k + 2) * 256 + n] + res0[(k + 2) * 256 + n];
    else if (k < 130) v = W0[(k - 128) * 256 + n];
    else if (k < 132) v = res0[(k - 130) * 256 + n];
  } else if (idx < 303104){
    int rem = idx - 40960;
    int seg = rem >> 16;
    int r2 = rem & 65535;
    int n = r2 >> 8, k = r2 & 255;
    const float* src = (seg == 0) ? W1 : (seg == 1) ? W2 : (seg == 2) ? W3 : hW1;
    v = src[k * 256 + n];
    if (seg < 3) v *= (1.f / 3.f);
  } else {
    int rem = idx - 303104;
    int n = rem >> 8, k = rem & 255;
    if (n < 2) v = hW2[k * 2 + n];
  }
  ws[idx] = f2bf(v);
}

// ---------------------------------------------------------------------------
// temb: silu(sinusoidal(t) @ time_W + time_b) per batch element -> bf16
// ---------------------------------------------------------------------------
__global__ void temb_kernel(const int* __restrict__ t, const float* __restrict__ tW,
                            const float* __restrict__ tb, short* __restrict__ temb){
  __shared__ float sc[128];
  int b = blockIdx.x, n = threadIdx.x;  // 128 threads
  float tv = (float)t[b];
  {
    int j = n & 63;
    float fr = __expf(-9.210340371976184f * (float)j * (1.f / 63.f));
    float ang = tv * fr;
    sc[n] = (n < 64) ? sinf(ang) : cosf(ang);
  }
  __syncthreads();
  float acc = tb[n];
  #pragma unroll 8
  for (int k = 0; k < 128; ++k) acc += sc[k] * tW[k * 128 + n];
  temb[b * 128 + n] = f2bf(silu_f(acc));
}

// ---------------------------------------------------------------------------
// mm2 (interleaved cols): acc[mt][0] ~ col n0+2*m15, acc[mt][1] ~ col
// n0+2*m15+1. B-frag tile0 = Wt row n0+2*m15, tile1 = next row. A-frag/C rows
// unchanged: row = 16*mt + (l&15) for A, (l>>4)*4+j for C.
// unroll 4: 8 weight loads in flight (2 latency-exposed steps per matmul,
// was 4 at unroll 2). Full unroll (8) spilled — R4.
// ---------------------------------------------------------------------------
template<int KPAD>
__device__ __forceinline__ void mm2(const char* hbuf, const short* __restrict__ Wt,
                                    int m15, int g, int n0, f32x4 acc[5][2]){
  const short* wb = Wt + (n0 + 2 * m15) * KPAD + g * 8;
  #pragma unroll 4
  for (int ks = 0; ks < KPAD / 32; ++ks){
    bf16x8 bf0 = *(const bf16x8*)(wb + ks * 32);
    bf16x8 bf1 = *(const bf16x8*)(wb + KPAD + ks * 32);
    const int kb = ks * 64 + g * 16;
    #pragma unroll
    for (int mt = 0; mt < 5; ++mt){
      const int row = mt * 16 + m15;
      bf16x8 a = *(const bf16x8*)(hbuf + row * 512 + (kb ^ ((row & 7) << 4)));
      acc[mt][0] = __builtin_amdgcn_mfma_f32_16x16x32_bf16(a, bf0, acc[mt][0], 0, 0, 0);
      acc[mt][1] = __builtin_amdgcn_mfma_f32_16x16x32_bf16(a, bf1, acc[mt][1], 0, 0, 0);
    }
  }
}

// ---------------------------------------------------------------------------
// Fused GCN. Grid (16, 512): x = 64-vertex tile, y = batch. 512 thr = 8 waves,
// wave w owns output cols [32w, 32w+32) (interleaved pairing inside). LDS:
// hA + hB, each 80x256 bf16 (40KB). Row r <-> vertex (v0 + r - 4) mod 1024;
// valid window shrinks 1/layer; out rows 4..67. Buffer flow:
// stage->hA; L0: hA->hB; L1: hB->hA; L2: hA->hB; L3: hB->hA; head1: hA->hB;
// head2: hB->out. ONE barrier per phase; residual for layer L re-read from
// bin (read-only during the phase — no hazard, no regs).
// ---------------------------------------------------------------------------
__global__ __launch_bounds__(512, 4)
void gcn_fused(const float* __restrict__ x, const short* __restrict__ ws,
               const float* __restrict__ b0p, const float* __restrict__ b1p,
               const float* __restrict__ b2p, const float* __restrict__ b3p,
               const float* __restrict__ hb1p, const float* __restrict__ hb2p,
               float* __restrict__ out){
  extern __shared__ char lds[];
  char* const hA = lds;
  char* const hB = lds + 40960;
  const int tid = threadIdx.x;
  const int lane = tid & 63, wid = tid >> 6;
  const int m15 = lane & 15, g = lane >> 4;
  const int n0 = wid * 32;
  const int cb2 = (n0 + 2 * m15) * 2;   // byte col of this thread's col pair
  const int b = blockIdx.y, v0 = blockIdx.x * 64;

  // ---- stage h0' into hA: temb chunks 0-15; chunk 16 = [cagg0,cagg1,c0,c1,0..];
  //      chunks 17-23 zero. (Layer-0 A-row = [temb, cagg, c] vs merged W0T.)
  {
    const short* tembp = ws + OFF_TEMB + b * 128;
    for (int task = tid; task < 72 * 16; task += 512){
      int r = task >> 4, ck = (task & 15) * 16;
      *(bf16x8*)(hA + r * 512 + (ck ^ ((r & 7) << 4))) =
          *(const bf16x8*)(tembp + (task & 15) * 8);
    }
    for (int task = tid; task < 80 * 8; task += 512){
      int r = task >> 3, q = task & 7;
      bf16x8 v = {0, 0, 0, 0, 0, 0, 0, 0};
      if (q == 0 && r < 72){
        const float* xb = x + b * 2048;
        int vm = (v0 + r - 5) & (NV - 1);
        int vc = (v0 + r - 4) & (NV - 1);
        int vp = (v0 + r - 3) & (NV - 1);
        float c0m = xb[vm * 2], c1m = xb[vm * 2 + 1];
        float c0c = xb[vc * 2], c1c = xb[vc * 2 + 1];
        float c0p = xb[vp * 2], c1p = xb[vp * 2 + 1];
        v[0] = f2bf((c0m + c0c + c0p) * (1.f / 3.f));
        v[1] = f2bf((c1m + c1c + c1p) * (1.f / 3.f));
        v[2] = f2bf(c0c);
        v[3] = f2bf(c1c);
      }
      *(bf16x8*)(hA + r * 512 + (((16 + q) * 16) ^ ((r & 7) << 4))) = v;
    }
  }
  __syncthreads();

  f32x4 acc[5][2];

  // ---- layer 0: ONE matmul (merged weights); h1 = silu(acc+b0): hA -> hB ----
  {
    const float2 bias = *(const float2*)(b0p + n0 + 2 * m15);
    #pragma unroll
    for (int mt = 0; mt < 5; ++mt){ acc[mt][0] = zero4(); acc[mt][1] = zero4(); }
    mm2<160>(hA, ws + OFF_W0T, m15, g, n0, acc);
    #pragma unroll
    for (int mt = 0; mt < 5; ++mt){
      const int row0 = mt * 16 + g * 4;
      #pragma unroll
      for (int j = 0; j < 4; ++j){
        const int row = row0 + j;
        const int ad = row * 512 + (cb2 ^ ((row & 7) << 4));
        *(unsigned int*)(hB + ad) =
            pack2_silu(acc[mt][0][j] + bias.x, acc[mt][1][j] + bias.y);
      }
    }
  }
  __syncthreads();

  // ---- layers 1..3: h = silu(agg(h@W') + b + h); W' pre-scaled by 1/3;
  //      agg via in-reg shfl; residual read from bin (read-only this phase) ----
  #pragma unroll
  for (int L = 0; L < 3; ++L){
    const char* bin  = (L & 1) ? hA : hB;
    char*       bout = (L & 1) ? hB : hA;
    const short* Wt = ws + (L == 0 ? OFF_W1T : L == 1 ? OFF_W2T : OFF_W3T);
    const float* bp = (L == 0 ? b1p : L == 1 ? b2p : b3p);
    const float2 bias = *(const float2*)(bp + n0 + 2 * m15);
    #pragma unroll
    for (int mt = 0; mt < 5; ++mt){ acc[mt][0] = zero4(); acc[mt][1] = zero4(); }
    mm2<256>(bin, Wt, m15, g, n0, acc);
    #pragma unroll
    for (int mt = 0; mt < 5; ++mt){
      // ring neighbors at the j=0 / j=3 group boundary (row-1 / row+1);
      // source pre-selects mt-1 at g==3 / mt+1 at g==0
      float pm0[2], pp3[2];
      #pragma unroll
      for (int nt = 0; nt < 2; ++nt){
        float upv = (g == 3) ? acc[mt > 0 ? mt - 1 : 0][nt][3] : acc[mt][nt][3];
        pm0[nt] = __shfl(upv, (lane + 48) & 63);
        float dnv = (g == 0) ? acc[mt < 4 ? mt + 1 : 4][nt][0] : acc[mt][nt][0];
        pp3[nt] = __shfl(dnv, (lane + 16) & 63);
      }
      const int row0 = mt * 16 + g * 4;
      #pragma unroll
      for (int j = 0; j < 4; ++j){
        const int row = row0 + j;
        const int ad = row * 512 + (cb2 ^ ((row & 7) << 4));
        const unsigned int rr = *(const unsigned int*)(bin + ad);
        union { unsigned int i; float f; } re, ro;
        re.i = rr << 16;            // residual, even col
        ro.i = rr & 0xffff0000u;    // residual, odd col
        float p0 = (j == 0) ? pm0[0] : acc[mt][0][j - 1];
        float n0v = (j == 3) ? pp3[0] : acc[mt][0][j + 1];
        float p1 = (j == 0) ? pm0[1] : acc[mt][1][j - 1];
        float n1v = (j == 3) ? pp3[1] : acc[mt][1][j + 1];
        float s0 = p0 + acc[mt][0][j] + n0v + bias.x + re.f;
        float s1 = p1 + acc[mt][1][j] + n1v + bias.y + ro.f;
        *(unsigned int*)(bout + ad) = pack2_silu(s0, s1);
      }
    }
    __syncthreads();
  }
  // h4 now in hA.

  // ---- head part 1: u = silu(h4 @ hW1 + hb1): hA -> hB ----
  {
    const float2 bias = *(const float2*)(hb1p + n0 + 2 * m15);
    #pragma unroll
    for (int mt = 0; mt < 5; ++mt){ acc[mt][0] = zero4(); acc[mt][1] = zero4(); }
    mm2<256>(hA, ws + OFF_HW1T, m15, g, n0, acc);
    #pragma unroll
    for (int mt = 0; mt < 5; ++mt){
      const int row0 = mt * 16 + g * 4;
      #pragma unroll
      for (int j = 0; j < 4; ++j){
        const int row = row0 + j;
        const int ad = row * 512 + (cb2 ^ ((row & 7) << 4));
        *(unsigned int*)(hB + ad) =
            pack2_silu(acc[mt][0][j] + bias.x, acc[mt][1][j] + bias.y);
      }
    }
    __syncthreads();
  }

  // ---- head part 2 (waves 0-4, one mt each): out = u @ hW2 + hb2, rows 4..67 ----
  if (wid < 5){
    f32x4 a2 = zero4();
    const short* wb = ws + OFF_HW2T + m15 * 256 + g * 8;
    const int row = wid * 16 + m15;
    const int rsw = row * 512;
    #pragma unroll 4
    for (int ks = 0; ks < 8; ++ks){
      bf16x8 bfr = *(const bf16x8*)(wb + ks * 32);
      const int kb = ks * 64 + g * 16;
      bf16x8 a = *(const bf16x8*)(hB + rsw + (kb ^ ((row & 7) << 4)));
      a2 = __builtin_amdgcn_mfma_f32_16x16x32_bf16(a, bfr, a2, 0, 0, 0);
    }
    if (m15 < 2){
      float bias = hb2p[m15];
      #pragma unroll
      for (int j = 0; j < 4; ++j){
        int orow = wid * 16 + g * 4 + j;
        if (orow >= 4 && orow < 68)
          out[b * 2048 + (v0 + orow - 4) * 2 + m15] = a2[j] + bias;
      }
    }
  }
}

// ---------------------------------------------------------------------------
extern "C" void kernel_launch(void* const* d_in, const int* in_sizes, int n_in,
                              void* d_out, int out_size, void* d_ws, size_t ws_size,
                              hipStream_t stream){
  const float* x   = (const float*)d_in[0];
  const int*   t   = (const int*)  d_in[1];
  const float* tW  = (const float*)d_in[2];
  const float* tb  = (const float*)d_in[3];
  const float* W0  = (const float*)d_in[4];
  const float* b0  = (const float*)d_in[5];
  const float* W1  = (const float*)d_in[6];
  const float* b1  = (const float*)d_in[7];
  const float* W2  = (const float*)d_in[8];
  const float* b2  = (const float*)d_in[9];
  const float* W3  = (const float*)d_in[10];
  const float* b3  = (const float*)d_in[11];
  const float* res0= (const float*)d_in[12];
  const float* hW1 = (const float*)d_in[13];
  const float* hb1 = (const float*)d_in[14];
  const float* hW2 = (const float*)d_in[15];
  const float* hb2 = (const float*)d_in[16];
  short* ws  = (short*)d_ws;
  float* out = (float*)d_out;

  hipFuncSetAttribute((const void*)gcn_fused,
                      hipFuncAttributeMaxDynamicSharedMemorySize, 81920);

  prep_kernel<<<dim3((PREP_ELEMS + 255) / 256), dim3(256), 0, stream>>>(
      W0, res0, W1, W2, W3, hW1, hW2, ws);
  temb_kernel<<<dim3(512), dim3(128), 0, stream>>>(t, tW, tb, ws + OFF_TEMB);
  gcn_fused<<<dim3(16, 512), dim3(512), 81920, stream>>>(
      x, ws, b0, b1, b2, b3, hb1, hb2, out);
}

// Round 11
// 711.968 us; speedup vs baseline: 1.1172x; 1.0921x over previous
//
#include <hip/hip_runtime.h>
#include <hip/hip_bf16.h>

// ---------------------------------------------------------------------------
// DenoiseGCN fused kernel for MI355X (gfx950) — round 11.
// R10 post-mortem: corrected MFMA cost model (19 cyc/SIMD per 16x16x32) says
// matrix ~28%, VALU ~52%, LDS ~35% — lockstep-phase bound, no pipe saturated.
// This round deletes work: layer 0 is rank-5 (temb rows are row-invariant,
// coords are rank-4) -> tv = temb@(W0+res0)_temb + b0 precomputed per batch
// in the temb kernel (f32); fused L0 = outer-product epilogue. Deletes the
// mm2<160> (970 matrix-cyc/wave), the whole temb-staging phase, one barrier.
// Adds s_setprio(1) around mm2 MFMA loops (T5) to favor MFMA-issuing waves.
// ---------------------------------------------------------------------------

typedef __attribute__((ext_vector_type(8))) short bf16x8;
typedef __attribute__((ext_vector_type(4))) float f32x4;

#define NV 1024

// ws layout: bf16 region then f32 region
#define OFF_W1T   0        // [256][256] bf16, [n][k], pre-scaled 1/3
#define OFF_W2T   65536
#define OFF_W3T   131072
#define OFF_HW1T  196608
#define OFF_HW2T  262144   // [16][256]
#define BF16_ELEMS 266240
#define CW_BYTE   532480               // f32 cw[4][256]: W0c0,W0c1,res0c0,res0c1
#define TV_BYTE   536576               // f32 tv[512][256]
#define PREP_TOTAL (BF16_ELEMS + 1024)

__device__ __forceinline__ short f2bf(float f){
  __hip_bfloat16 h = __float2bfloat16(f);
  return *reinterpret_cast<short*>(&h);
}
__device__ __forceinline__ float bf2f(short u){
  union { unsigned int i; float f; } v;
  v.i = ((unsigned int)(unsigned short)u) << 16;
  return v.f;
}
__device__ __forceinline__ float silu_f(float v){
  float e = __expf(-v);
  return v * __builtin_amdgcn_rcpf(1.f + e);
}
__device__ __forceinline__ f32x4 zero4(){ f32x4 z = {0.f,0.f,0.f,0.f}; return z; }
__device__ __forceinline__ unsigned int pack2_silu(float s0, float s1){
  return (unsigned int)(unsigned short)f2bf(silu_f(s0))
       | ((unsigned int)(unsigned short)f2bf(silu_f(s1)) << 16);
}

// ---------------------------------------------------------------------------
// prep: W1..W3 (x1/3), hW1 -> bf16 [n][k]; hW2 -> bf16 [16][256];
// cw f32 = coord rows of W0/res0.
// ---------------------------------------------------------------------------
__global__ void prep_kernel(const float* __restrict__ W0, const float* __restrict__ res0,
                            const float* __restrict__ W1, const float* __restrict__ W2,
                            const float* __restrict__ W3, const float* __restrict__ hW1,
                            const float* __restrict__ hW2, short* __restrict__ ws){
  int idx = blockIdx.x * 256 + threadIdx.x;
  if (idx >= PREP_TOTAL) return;
  if (idx < BF16_ELEMS){
    float v;
    if (idx < 262144){
      int seg = idx >> 16;
      int r2 = idx & 65535;
      int n = r2 >> 8, k = r2 & 255;
      const float* src = (seg == 0) ? W1 : (seg == 1) ? W2 : (seg == 2) ? W3 : hW1;
      v = src[k * 256 + n];
      if (seg < 3) v *= (1.f / 3.f);
    } else {
      int rem = idx - 262144;
      int n = rem >> 8, k = rem & 255;
      v = (n < 2) ? hW2[k * 2 + n] : 0.f;
    }
    ws[idx] = f2bf(v);
  } else {
    int i = idx - BF16_ELEMS;           // 0..1023
    int d = i >> 8, n = i & 255;
    float v = (d < 2) ? W0[d * 256 + n] : res0[(d - 2) * 256 + n];
    ((float*)((char*)ws + CW_BYTE))[i] = v;
  }
}

// ---------------------------------------------------------------------------
// temb+tv: tmb = silu(sinusoidal(t) @ time_W + time_b)  (128)
//          tv[n] = b0[n] + sum_k tmb[k] * (W0[k+2][n] + res0[k+2][n])  (f32)
// one block (256 thr) per batch element.
// ---------------------------------------------------------------------------
__global__ void temb_kernel(const int* __restrict__ t, const float* __restrict__ tW,
                            const float* __restrict__ tb, const float* __restrict__ W0,
                            const float* __restrict__ res0, const float* __restrict__ b0,
                            float* __restrict__ tv){
  __shared__ float sc[128];
  __shared__ float tmb[128];
  int b = blockIdx.x, n = threadIdx.x;  // 256 threads
  float tvt = (float)t[b];
  if (n < 128){
    int j = n & 63;
    float fr = __expf(-9.210340371976184f * (float)j * (1.f / 63.f));
    float ang = tvt * fr;
    sc[n] = (n < 64) ? sinf(ang) : cosf(ang);
  }
  __syncthreads();
  if (n < 128){
    float acc = tb[n];
    #pragma unroll 8
    for (int k = 0; k < 128; ++k) acc += sc[k] * tW[k * 128 + n];
    tmb[n] = silu_f(acc);
  }
  __syncthreads();
  float acc2 = b0[n];
  #pragma unroll 4
  for (int k = 0; k < 128; ++k)
    acc2 += tmb[k] * (W0[(k + 2) * 256 + n] + res0[(k + 2) * 256 + n]);
  tv[b * 256 + n] = acc2;
}

// ---------------------------------------------------------------------------
// mm2 (interleaved cols): acc[mt][0] ~ col n0+2*m15, acc[mt][1] ~ next col.
// A: row = 16*mt + (l&15); C rows (l>>4)*4+j. unroll 4 (full unroll spilled).
// setprio(1) keeps MFMA-issuing waves favored once waves drift (T5).
// ---------------------------------------------------------------------------
__device__ __forceinline__ void mm2_256(const char* hbuf, const short* __restrict__ Wt,
                                        int m15, int g, int n0, f32x4 acc[5][2]){
  const short* wb = Wt + (n0 + 2 * m15) * 256 + g * 8;
  __builtin_amdgcn_s_setprio(1);
  #pragma unroll 4
  for (int ks = 0; ks < 8; ++ks){
    bf16x8 bf0 = *(const bf16x8*)(wb + ks * 32);
    bf16x8 bf1 = *(const bf16x8*)(wb + 256 + ks * 32);
    const int kb = ks * 64 + g * 16;
    #pragma unroll
    for (int mt = 0; mt < 5; ++mt){
      const int row = mt * 16 + m15;
      bf16x8 a = *(const bf16x8*)(hbuf + row * 512 + (kb ^ ((row & 7) << 4)));
      acc[mt][0] = __builtin_amdgcn_mfma_f32_16x16x32_bf16(a, bf0, acc[mt][0], 0, 0, 0);
      acc[mt][1] = __builtin_amdgcn_mfma_f32_16x16x32_bf16(a, bf1, acc[mt][1], 0, 0, 0);
    }
  }
  __builtin_amdgcn_s_setprio(0);
}

// ---------------------------------------------------------------------------
// Fused GCN. Grid (16, 512). 512 thr = 8 waves, wave w owns cols [32w,32w+32)
// (interleaved pairing). LDS: hA + hB 40KB each; cc (80 x f32x4, 1.28KB)
// overlays hB during L0 (hB dead there). Row r <-> vertex (v0+r-4) mod 1024.
// Flow: stage cc->hB | L0: cc->hA | L1: hA->hB | L2: hB->hA | L3: hA->hB |
// head1: hB->hA | head2: hA->out.  6 barriers.
// ---------------------------------------------------------------------------
__global__ __launch_bounds__(512, 4)
void gcn_fused(const float* __restrict__ x, const short* __restrict__ ws,
               const float* __restrict__ tvp, const float* __restrict__ cwf,
               const float* __restrict__ b1p, const float* __restrict__ b2p,
               const float* __restrict__ b3p, const float* __restrict__ hb1p,
               const float* __restrict__ hb2p, float* __restrict__ out){
  extern __shared__ char lds[];
  char* const hA = lds;
  char* const hB = lds + 40960;
  const int tid = threadIdx.x;
  const int lane = tid & 63, wid = tid >> 6;
  const int m15 = lane & 15, g = lane >> 4;
  const int n0 = wid * 32;
  const int col0 = n0 + 2 * m15;
  const int cb2 = col0 * 2;             // byte col of this thread's col pair
  const int b = blockIdx.y, v0 = blockIdx.x * 64;

  // ---- stage cc[r] = (cagg0, cagg1, c0, c1) f32 into hB[0:1280) ----
  if (tid < 80){
    const int r = tid;
    const float* xb = x + b * 2048;
    int vm = (v0 + r - 5) & (NV - 1);
    int vc = (v0 + r - 4) & (NV - 1);
    int vp = (v0 + r - 3) & (NV - 1);
    float c0m = xb[vm * 2], c1m = xb[vm * 2 + 1];
    float c0c = xb[vc * 2], c1c = xb[vc * 2 + 1];
    float c0p = xb[vp * 2], c1p = xb[vp * 2 + 1];
    f32x4 cc;
    cc[0] = (c0m + c0c + c0p) * (1.f / 3.f);
    cc[1] = (c1m + c1c + c1p) * (1.f / 3.f);
    cc[2] = c0c;
    cc[3] = c1c;
    *(f32x4*)(hB + r * 16) = cc;
  }
  __syncthreads();

  // ---- layer 0 (rank-5): h1 = silu(tv + cagg@W0c + c@res0c): cc -> hA ----
  {
    const float2 tv2 = *(const float2*)(tvp + b * 256 + col0);
    const float2 wA = *(const float2*)(cwf + col0);
    const float2 wB = *(const float2*)(cwf + 256 + col0);
    const float2 wC = *(const float2*)(cwf + 512 + col0);
    const float2 wD = *(const float2*)(cwf + 768 + col0);
    #pragma unroll
    for (int mt = 0; mt < 5; ++mt){
      const int row0 = mt * 16 + g * 4;
      #pragma unroll
      for (int j = 0; j < 4; ++j){
        const int row = row0 + j;
        const f32x4 cc = *(const f32x4*)(hB + row * 16);
        float s0 = tv2.x + cc[0] * wA.x + cc[1] * wB.x + cc[2] * wC.x + cc[3] * wD.x;
        float s1 = tv2.y + cc[0] * wA.y + cc[1] * wB.y + cc[2] * wC.y + cc[3] * wD.y;
        const int ad = row * 512 + (cb2 ^ ((row & 7) << 4));
        *(unsigned int*)(hA + ad) = pack2_silu(s0, s1);
      }
    }
  }
  __syncthreads();

  f32x4 acc[5][2];

  // ---- layers 1..3: h = silu(agg(h@W') + b + h); W' pre-scaled 1/3;
  //      agg via in-reg shfl; residual read from bin (read-only this phase) ----
  #pragma unroll
  for (int L = 0; L < 3; ++L){
    const char* bin  = (L & 1) ? hB : hA;
    char*       bout = (L & 1) ? hA : hB;
    const short* Wt = ws + (L == 0 ? OFF_W1T : L == 1 ? OFF_W2T : OFF_W3T);
    const float* bp = (L == 0 ? b1p : L == 1 ? b2p : b3p);
    const float2 bias = *(const float2*)(bp + col0);
    #pragma unroll
    for (int mt = 0; mt < 5; ++mt){ acc[mt][0] = zero4(); acc[mt][1] = zero4(); }
    mm2_256(bin, Wt, m15, g, n0, acc);
    #pragma unroll
    for (int mt = 0; mt < 5; ++mt){
      // ring neighbors at the j=0 / j=3 group boundary (row-1 / row+1);
      // source pre-selects mt-1 at g==3 / mt+1 at g==0
      float pm0[2], pp3[2];
      #pragma unroll
      for (int nt = 0; nt < 2; ++nt){
        float upv = (g == 3) ? acc[mt > 0 ? mt - 1 : 0][nt][3] : acc[mt][nt][3];
        pm0[nt] = __shfl(upv, (lane + 48) & 63);
        float dnv = (g == 0) ? acc[mt < 4 ? mt + 1 : 4][nt][0] : acc[mt][nt][0];
        pp3[nt] = __shfl(dnv, (lane + 16) & 63);
      }
      const int row0 = mt * 16 + g * 4;
      #pragma unroll
      for (int j = 0; j < 4; ++j){
        const int row = row0 + j;
        const int ad = row * 512 + (cb2 ^ ((row & 7) << 4));
        const unsigned int rr = *(const unsigned int*)(bin + ad);
        union { unsigned int i; float f; } re, ro;
        re.i = rr << 16;            // residual, even col
        ro.i = rr & 0xffff0000u;    // residual, odd col
        float p0 = (j == 0) ? pm0[0] : acc[mt][0][j - 1];
        float n0v = (j == 3) ? pp3[0] : acc[mt][0][j + 1];
        float p1 = (j == 0) ? pm0[1] : acc[mt][1][j - 1];
        float n1v = (j == 3) ? pp3[1] : acc[mt][1][j + 1];
        float s0 = p0 + acc[mt][0][j] + n0v + bias.x + re.f;
        float s1 = p1 + acc[mt][1][j] + n1v + bias.y + ro.f;
        *(unsigned int*)(bout + ad) = pack2_silu(s0, s1);
      }
    }
    __syncthreads();
  }
  // h4 now in hB.

  // ---- head part 1: u = silu(h4 @ hW1 + hb1): hB -> hA ----
  {
    const float2 bias = *(const float2*)(hb1p + col0);
    #pragma unroll
    for (int mt = 0; mt < 5; ++mt){ acc[mt][0] = zero4(); acc[mt][1] = zero4(); }
    mm2_256(hB, ws + OFF_HW1T, m15, g, n0, acc);
    #pragma unroll
    for (int mt = 0; mt < 5; ++mt){
      const int row0 = mt * 16 + g * 4;
      #pragma unroll
      for (int j = 0; j < 4; ++j){
        const int row = row0 + j;
        const int ad = row * 512 + (cb2 ^ ((row & 7) << 4));
        *(unsigned int*)(hA + ad) =
            pack2_silu(acc[mt][0][j] + bias.x, acc[mt][1][j] + bias.y);
      }
    }
    __syncthreads();
  }

  // ---- head part 2 (waves 0-4, one mt each): out = u @ hW2 + hb2, rows 4..67 ----
  if (wid < 5){
    f32x4 a2 = zero4();
    const short* wb = ws + OFF_HW2T + m15 * 256 + g * 8;
    const int row = wid * 16 + m15;
    const int rsw = row * 512;
    #pragma unroll 4
    for (int ks = 0; ks < 8; ++ks){
      bf16x8 bfr = *(const bf16x8*)(wb + ks * 32);
      const int kb = ks * 64 + g * 16;
      bf16x8 a = *(const bf16x8*)(hA + rsw + (kb ^ ((row & 7) << 4)));
      a2 = __builtin_amdgcn_mfma_f32_16x16x32_bf16(a, bfr, a2, 0, 0, 0);
    }
    if (m15 < 2){
      float bias = hb2p[m15];
      #pragma unroll
      for (int j = 0; j < 4; ++j){
        int orow = wid * 16 + g * 4 + j;
        if (orow >= 4 && orow < 68)
          out[b * 2048 + (v0 + orow - 4) * 2 + m15] = a2[j] + bias;
      }
    }
  }
}

// ---------------------------------------------------------------------------
extern "C" void kernel_launch(void* const* d_in, const int* in_sizes, int n_in,
                              void* d_out, int out_size, void* d_ws, size_t ws_size,
                              hipStream_t stream){
  const float* x   = (const float*)d_in[0];
  const int*   t   = (const int*)  d_in[1];
  const float* tW  = (const float*)d_in[2];
  const float* tb  = (const float*)d_in[3];
  const float* W0  = (const float*)d_in[4];
  const float* b0  = (const float*)d_in[5];
  const float* W1  = (const float*)d_in[6];
  const float* b1  = (const float*)d_in[7];
  const float* W2  = (const float*)d_in[8];
  const float* b2  = (const float*)d_in[9];
  const float* W3  = (const float*)d_in[10];
  const float* b3  = (const float*)d_in[11];
  const float* res0= (const float*)d_in[12];
  const float* hW1 = (const float*)d_in[13];
  const float* hb1 = (const float*)d_in[14];
  const float* hW2 = (const float*)d_in[15];
  const float* hb2 = (const float*)d_in[16];
  short* ws  = (short*)d_ws;
  float* tvp = (float*)((char*)d_ws + TV_BYTE);
  float* cwf = (float*)((char*)d_ws + CW_BYTE);
  float* out = (float*)d_out;

  hipFuncSetAttribute((const void*)gcn_fused,
                      hipFuncAttributeMaxDynamicSharedMemorySize, 81920);

  prep_kernel<<<dim3((PREP_TOTAL + 255) / 256), dim3(256), 0, stream>>>(
      W0, res0, W1, W2, W3, hW1, hW2, ws);
  temb_kernel<<<dim3(512), dim3(256), 0, stream>>>(t, tW, tb, W0, res0, b0, tvp);
  gcn_fused<<<dim3(16, 512), dim3(512), 81920, stream>>>(
      x, ws, tvp, cwf, b1, b2, b3, hb1, hb2, out);
}